// Round 4
// baseline (475.590 us; speedup 1.0000x reference)
//
#include <hip/hip_runtime.h>

#define NBINS 12
#define GRID1 2048
#define BLK 256

// Single fused kernel.
// ws layout: float bins[13] (12 cross bins + sumsq at [12]), uint counter at [13].
// All 14 words pre-zeroed by a hipMemsetAsync node in kernel_launch.
__global__ __launch_bounds__(BLK) void umse_fused(
    const float4* __restrict__ x4, const float4* __restrict__ t4,
    const int* __restrict__ batch32,
    float* __restrict__ bins, unsigned int* __restrict__ counter,
    float* __restrict__ out, int nNodes)
{
    __shared__ float cross_lds[NBINS];
    __shared__ float redA[BLK / 64], redB[BLK / 64];
    __shared__ int s_info[3];      // is64, g_first, g_last
    __shared__ unsigned s_done;
    __shared__ float fbins[13];

    const int tid = threadIdx.x;
    const int lane = tid & 63;
    const int wid = tid >> 6;

    const int total = nNodes * 16;                        // float4 count (D=64)
    const int per_block = (total + GRID1 - 1) / GRID1;    // contiguous chunk
    const int start = blockIdx.x * per_block;
    const int end = min(start + per_block, total);

    if (tid == 0) {
        // int32 batch: last slot is a small positive int. int64 viewed as
        // int32: slot nNodes-1 is the high word of a mid-array element -> 0.
        int is64 = (batch32[nNodes - 1] == 0) ? 1 : 0;
        int n0 = start >> 4;
        int n1 = (end - 1) >> 4;
        s_info[0] = is64;
        s_info[1] = is64 ? batch32[n0 << 1] : batch32[n0];
        s_info[2] = is64 ? batch32[n1 << 1] : batch32[n1];
    }
    if (tid < NBINS) cross_lds[tid] = 0.0f;
    __syncthreads();
    const int is64 = s_info[0];
    const int gfirst = s_info[1], glast = s_info[2];

    float sumsq = 0.0f;
    float dot = 0.0f;

    const bool fast = (gfirst == glast) && (end - start == 8 * BLK);

    if (fast) {
        // Branch-free hot loop: 16 independent float4 loads, full MLP.
        const float4* xa = x4 + start + tid;
        const float4* ta = t4 + start + tid;
        #pragma unroll
        for (int k = 0; k < 8; ++k) {
            float4 a = xa[k * BLK];
            float4 b = ta[k * BLK];
            sumsq += a.x * a.x + a.y * a.y + a.z * a.z + a.w * a.w
                   + b.x * b.x + b.y * b.y + b.z * b.z + b.w * b.w;
            dot   += a.x * b.x + a.y * b.y + a.z * b.z + a.w * b.w;
        }
    } else {
        // Rare (block straddles a graph boundary): per-element batch lookup.
        float acc = 0.0f;
        int curg = -1;
        for (int idx = start + tid; idx < end; idx += BLK) {
            float4 a = x4[idx];
            float4 b = t4[idx];
            int node = idx >> 4;
            int g = is64 ? batch32[node << 1] : batch32[node];
            sumsq += a.x * a.x + a.y * a.y + a.z * a.z + a.w * a.w
                   + b.x * b.x + b.y * b.y + b.z * b.z + b.w * b.w;
            float p = a.x * b.x + a.y * b.y + a.z * b.z + a.w * b.w;
            if (g != curg) {
                if (curg >= 0) atomicAdd(&cross_lds[curg], acc);
                curg = g;
                acc = p;
            } else {
                acc += p;
            }
        }
        if (curg >= 0) atomicAdd(&cross_lds[curg], acc);
    }

    // Block reduction of sumsq (and dot in the fast path).
    for (int m = 32; m; m >>= 1) {
        sumsq += __shfl_xor(sumsq, m);
        dot   += __shfl_xor(dot, m);
    }
    if (lane == 0) { redA[wid] = sumsq; redB[wid] = dot; }
    __syncthreads();   // also orders slow-path LDS atomics

    if (tid == 0) {
        atomicAdd(&bins[12], redA[0] + redA[1] + redA[2] + redA[3]);
        if (fast)
            atomicAdd(&bins[gfirst], redB[0] + redB[1] + redB[2] + redB[3]);
    }
    if (!fast && tid < NBINS) {
        float v = cross_lds[tid];
        if (v != 0.0f) atomicAdd(&bins[tid], v);
    }

    // Completion protocol: release bins, count, last block finalizes.
    __threadfence();
    if (tid == 0) s_done = atomicAdd(counter, 1u);
    __syncthreads();
    if (s_done == GRID1 - 1) {
        __threadfence();   // acquire
        if (tid < 13)
            fbins[tid] = __hip_atomic_load(&bins[tid], __ATOMIC_RELAXED,
                                           __HIP_MEMORY_SCOPE_AGENT);
        __syncthreads();
        if (tid == 0) {
            float acc = 0.0f;
            for (int g = 0; g < NBINS; ++g) acc += fabsf(fbins[g]);
            out[0] = fbins[12] - 2.0f * acc;
        }
    }
}

extern "C" void kernel_launch(void* const* d_in, const int* in_sizes, int n_in,
                              void* d_out, int out_size, void* d_ws, size_t ws_size,
                              hipStream_t stream)
{
    const float* x = (const float*)d_in[0];
    const float* t = (const float*)d_in[1];
    const int* batch = (const int*)d_in[2];
    const int nNodes = in_sizes[2];   // N = 262144
    float* bins = (float*)d_ws;
    unsigned int* counter = (unsigned int*)((float*)d_ws + 13);
    float* out = (float*)d_out;

    hipMemsetAsync(d_ws, 0, 64, stream);
    umse_fused<<<GRID1, BLK, 0, stream>>>(
        (const float4*)x, (const float4*)t, batch, bins, counter, out, nNodes);
}

// Round 5
// 160.474 us; speedup vs baseline: 2.9637x; 2.9637x over previous
//
#include <hip/hip_runtime.h>

#define NBINS 12
#define GRID1 2048
#define BLK 256

// Kernel 1: per-block partials over a CONTIGUOUS float4 chunk. NO global atomics.
// ws layout (transposed for coalesced kernel2 reads):
//   ws[g*GRID1 + block]  = cross_g partial (g<12)
//   ws[12*GRID1 + block] = sumsq partial
__global__ __launch_bounds__(BLK) void umse_partial(
    const float4* __restrict__ x4, const float4* __restrict__ t4,
    const int* __restrict__ batch32, float* __restrict__ ws, int nNodes)
{
    __shared__ float cross_lds[NBINS];
    __shared__ float redA[BLK / 64], redB[BLK / 64];
    __shared__ float s_sumsq;
    __shared__ int s_info[3];   // is64, g_first, g_last

    const int tid = threadIdx.x;
    const int lane = tid & 63;
    const int wid = tid >> 6;

    const int total = nNodes * 16;                        // float4 count (D=64)
    const int per_block = (total + GRID1 - 1) / GRID1;    // contiguous chunk
    const int start = blockIdx.x * per_block;
    const int end = min(start + per_block, total);

    if (tid < NBINS) cross_lds[tid] = 0.0f;
    if (tid == 0) {
        // int32 batch: last slot is a small positive int. int64 viewed as
        // int32: slot nNodes-1 is the high word of a mid-array element -> 0.
        int is64 = (batch32[nNodes - 1] == 0) ? 1 : 0;
        s_info[0] = is64;
        if (start < total) {
            int n0 = start >> 4;
            int n1 = (end - 1) >> 4;
            s_info[1] = is64 ? batch32[n0 << 1] : batch32[n0];
            s_info[2] = is64 ? batch32[n1 << 1] : batch32[n1];
        } else {
            s_info[1] = 0; s_info[2] = 0;
        }
    }
    __syncthreads();
    const int is64 = s_info[0];
    const int gfirst = s_info[1], glast = s_info[2];

    float sumsq = 0.0f;
    float dot = 0.0f;

    const bool fast = (gfirst == glast) && (end - start == 8 * BLK);

    if (fast) {
        // Branch-free hot loop, staged loads: 8 float4 loads in flight.
        const float4* xa = x4 + start + tid;
        const float4* ta = t4 + start + tid;
        #pragma unroll
        for (int kk = 0; kk < 2; ++kk) {
            float4 a[4], b[4];
            #pragma unroll
            for (int k = 0; k < 4; ++k) {
                a[k] = xa[(kk * 4 + k) * BLK];
                b[k] = ta[(kk * 4 + k) * BLK];
            }
            #pragma unroll
            for (int k = 0; k < 4; ++k) {
                sumsq += a[k].x * a[k].x + a[k].y * a[k].y
                       + a[k].z * a[k].z + a[k].w * a[k].w
                       + b[k].x * b[k].x + b[k].y * b[k].y
                       + b[k].z * b[k].z + b[k].w * b[k].w;
                dot   += a[k].x * b[k].x + a[k].y * b[k].y
                       + a[k].z * b[k].z + a[k].w * b[k].w;
            }
        }
    } else {
        // Rare (block straddles a graph boundary or ragged tail).
        float acc = 0.0f;
        int curg = -1;
        for (int idx = start + tid; idx < end; idx += BLK) {
            float4 a = x4[idx];
            float4 b = t4[idx];
            int node = idx >> 4;
            int g = is64 ? batch32[node << 1] : batch32[node];
            sumsq += a.x * a.x + a.y * a.y + a.z * a.z + a.w * a.w
                   + b.x * b.x + b.y * b.y + b.z * b.z + b.w * b.w;
            float p = a.x * b.x + a.y * b.y + a.z * b.z + a.w * b.w;
            if (g != curg) {
                if (curg >= 0) atomicAdd(&cross_lds[curg], acc);
                curg = g;
                acc = p;
            } else {
                acc += p;
            }
        }
        if (curg >= 0) atomicAdd(&cross_lds[curg], acc);
    }

    // Block reduction (shuffle within wave, LDS across waves).
    for (int m = 32; m; m >>= 1) {
        sumsq += __shfl_xor(sumsq, m);
        dot   += __shfl_xor(dot, m);
    }
    if (lane == 0) { redA[wid] = sumsq; redB[wid] = dot; }
    __syncthreads();   // also orders slow-path LDS atomics

    if (tid == 0) {
        s_sumsq = redA[0] + redA[1] + redA[2] + redA[3];
        if (fast) cross_lds[gfirst] = redB[0] + redB[1] + redB[2] + redB[3];
    }
    __syncthreads();

    if (tid < NBINS) ws[tid * GRID1 + blockIdx.x] = cross_lds[tid];
    if (tid == NBINS) ws[NBINS * GRID1 + blockIdx.x] = s_sumsq;
}

// Kernel 2: 13 waves, wave w reduces column w (contiguous, coalesced), fp64.
__global__ __launch_bounds__(832) void umse_final(
    const float* __restrict__ ws, float* __restrict__ out)
{
    __shared__ double cols[13];
    const int tid = threadIdx.x;
    const int w = tid >> 6, lane = tid & 63;

    double s = 0.0;
    for (int b = lane; b < GRID1; b += 64) s += (double)ws[w * GRID1 + b];
    for (int m = 32; m; m >>= 1) s += __shfl_xor(s, m);
    if (lane == 0) cols[w] = s;
    __syncthreads();

    if (tid == 0) {
        double acc = 0.0;
        for (int g = 0; g < NBINS; ++g) acc += fabs(cols[g]);
        out[0] = (float)(cols[12] - 2.0 * acc);
    }
}

extern "C" void kernel_launch(void* const* d_in, const int* in_sizes, int n_in,
                              void* d_out, int out_size, void* d_ws, size_t ws_size,
                              hipStream_t stream)
{
    const float* x = (const float*)d_in[0];
    const float* t = (const float*)d_in[1];
    const int* batch = (const int*)d_in[2];
    const int nNodes = in_sizes[2];   // N = 262144
    float* ws = (float*)d_ws;
    float* out = (float*)d_out;

    umse_partial<<<GRID1, BLK, 0, stream>>>(
        (const float4*)x, (const float4*)t, batch, ws, nNodes);
    umse_final<<<1, 832, 0, stream>>>(ws, out);
}

// Round 6
// 155.957 us; speedup vs baseline: 3.0495x; 1.0290x over previous
//
#include <hip/hip_runtime.h>

#define NBINS 12
#define GRID1 2048
#define BLK 256
#define STRIDE (GRID1 * BLK)

typedef float f4 __attribute__((ext_vector_type(4)));

__device__ __forceinline__ float dot4(f4 a, f4 b) {
    return a.x * b.x + a.y * b.y + a.z * b.z + a.w * b.w;
}
__device__ __forceinline__ float sq4(f4 a) {
    return a.x * a.x + a.y * a.y + a.z * a.z + a.w * a.w;
}
// 16-lane node-group reduce + one LDS atomic. Requires uniformly-active groups.
__device__ __forceinline__ void red16_atomic(float p, int g, float* cross, int lane) {
    p += __shfl_xor(p, 1);
    p += __shfl_xor(p, 2);
    p += __shfl_xor(p, 4);
    p += __shfl_xor(p, 8);
    if ((lane & 15) == 0) atomicAdd(&cross[g], p);
}

// Kernel 1: grid-stride (round-1 mapping, empirically fastest), nt loads,
// 2-way manual unroll (4 vector loads in flight), no serial prolog.
// ws layout: ws[c*GRID1 + block], c<12 = cross bins, c==12 = sumsq.
__global__ __launch_bounds__(BLK) void umse_partial(
    const f4* __restrict__ x4, const f4* __restrict__ t4,
    const int* __restrict__ batch32, float* __restrict__ ws, int nNodes)
{
    __shared__ float cross_lds[NBINS];
    __shared__ float redA[BLK / 64];

    const int tid = threadIdx.x;
    const int lane = tid & 63;

    if (tid < NBINS) cross_lds[tid] = 0.0f;
    // is64 probe: broadcast load (same line for all threads), no serial chain.
    // int32 batch: last slot is a small positive int. int64 viewed as int32:
    // slot nNodes-1 is the high word of a mid-array element -> 0.
    const int is64 = (batch32[nNodes - 1] == 0) ? 1 : 0;
    __syncthreads();

    const int total = nNodes * 16;        // float4 count (D=64 -> 16/node)
    const int nIter = total / STRIDE;     // 8 for N=262144 (exact)
    float sumsq = 0.0f;
    int idx = blockIdx.x * BLK + tid;

    int it = 0;
    for (; it + 1 < nIter; it += 2, idx += 2 * STRIDE) {
        const int i0 = idx, i1 = idx + STRIDE;
        // Issue all 4 vector loads before any consumer.
        f4 a0 = __builtin_nontemporal_load(x4 + i0);
        f4 b0 = __builtin_nontemporal_load(t4 + i0);
        f4 a1 = __builtin_nontemporal_load(x4 + i1);
        f4 b1 = __builtin_nontemporal_load(t4 + i1);
        const int n0 = i0 >> 4, n1 = i1 >> 4;
        const int g0 = is64 ? batch32[n0 << 1] : batch32[n0];
        const int g1 = is64 ? batch32[n1 << 1] : batch32[n1];
        sumsq += sq4(a0) + sq4(b0) + sq4(a1) + sq4(b1);
        red16_atomic(dot4(a0, b0), g0, cross_lds, lane);
        red16_atomic(dot4(a1, b1), g1, cross_lds, lane);
    }
    for (; it < nIter; ++it, idx += STRIDE) {
        f4 a = __builtin_nontemporal_load(x4 + idx);
        f4 b = __builtin_nontemporal_load(t4 + idx);
        const int n = idx >> 4;
        const int g = is64 ? batch32[n << 1] : batch32[n];
        sumsq += sq4(a) + sq4(b);
        red16_atomic(dot4(a, b), g, cross_lds, lane);
    }
    // Ragged tail (not taken for N=262144): per-thread atomic, no shuffles.
    if (idx < total) {
        f4 a = x4[idx];
        f4 b = t4[idx];
        const int n = idx >> 4;
        const int g = is64 ? batch32[n << 1] : batch32[n];
        sumsq += sq4(a) + sq4(b);
        atomicAdd(&cross_lds[g], dot4(a, b));
    }

    // Block reduction of sumsq.
    for (int m = 32; m; m >>= 1) sumsq += __shfl_xor(sumsq, m);
    if (lane == 0) redA[tid >> 6] = sumsq;
    __syncthreads();   // also orders the LDS atomics above

    if (tid < NBINS) ws[tid * GRID1 + blockIdx.x] = cross_lds[tid];
    if (tid == NBINS) {
        float s = 0.0f;
        #pragma unroll
        for (int w = 0; w < BLK / 64; ++w) s += redA[w];
        ws[NBINS * GRID1 + blockIdx.x] = s;
    }
}

// Kernel 2: 13 waves, wave w reduces column w (contiguous, coalesced), fp64.
__global__ __launch_bounds__(832) void umse_final(
    const float* __restrict__ ws, float* __restrict__ out)
{
    __shared__ double cols[13];
    const int tid = threadIdx.x;
    const int w = tid >> 6, lane = tid & 63;

    double s = 0.0;
    for (int b = lane; b < GRID1; b += 64) s += (double)ws[w * GRID1 + b];
    for (int m = 32; m; m >>= 1) s += __shfl_xor(s, m);
    if (lane == 0) cols[w] = s;
    __syncthreads();

    if (tid == 0) {
        double acc = 0.0;
        for (int g = 0; g < NBINS; ++g) acc += fabs(cols[g]);
        out[0] = (float)(cols[12] - 2.0 * acc);
    }
}

extern "C" void kernel_launch(void* const* d_in, const int* in_sizes, int n_in,
                              void* d_out, int out_size, void* d_ws, size_t ws_size,
                              hipStream_t stream)
{
    const float* x = (const float*)d_in[0];
    const float* t = (const float*)d_in[1];
    const int* batch = (const int*)d_in[2];
    const int nNodes = in_sizes[2];   // N = 262144
    float* ws = (float*)d_ws;
    float* out = (float*)d_out;

    umse_partial<<<GRID1, BLK, 0, stream>>>(
        (const f4*)x, (const f4*)t, batch, ws, nNodes);
    umse_final<<<1, 832, 0, stream>>>(ws, out);
}

// Round 7
// 154.198 us; speedup vs baseline: 3.0843x; 1.0114x over previous
//
#include <hip/hip_runtime.h>

#define NBINS 12
#define GRID1 2048
#define BLK 256
#define STRIDE (GRID1 * BLK)

typedef float f4 __attribute__((ext_vector_type(4)));

__device__ __forceinline__ float dot4(f4 a, f4 b) {
    return a.x * b.x + a.y * b.y + a.z * b.z + a.w * b.w;
}
__device__ __forceinline__ float sq4(f4 a) {
    return a.x * a.x + a.y * a.y + a.z * a.z + a.w * a.w;
}
// 16-lane node-group reduce + one LDS atomic. Requires uniformly-active groups.
__device__ __forceinline__ void red16_atomic(float p, int g, float* cross, int lane) {
    p += __shfl_xor(p, 1);
    p += __shfl_xor(p, 2);
    p += __shfl_xor(p, 4);
    p += __shfl_xor(p, 8);
    if ((lane & 15) == 0) atomicAdd(&cross[g], p);
}

// Kernel 1: grid-stride, nt loads, fully-static 8-iter fast path with ALL
// cross-lane work deferred to one post-loop flush (pure load+FMA hot loop).
// ws layout: ws[c*GRID1 + block], c<12 = cross bins, c==12 = sumsq.
__global__ __launch_bounds__(BLK) void umse_partial(
    const f4* __restrict__ x4, const f4* __restrict__ t4,
    const int* __restrict__ batch32, float* __restrict__ ws, int nNodes)
{
    __shared__ float cross_lds[NBINS];
    __shared__ float redA[BLK / 64];

    const int tid = threadIdx.x;
    const int lane = tid & 63;

    if (tid < NBINS) cross_lds[tid] = 0.0f;
    // int32 batch: last slot is a small positive int. int64 viewed as int32:
    // slot nNodes-1 is the high word of a mid-array element -> 0.
    const int is64 = (batch32[nNodes - 1] == 0) ? 1 : 0;
    __syncthreads();

    const int total = nNodes * 16;        // float4 count (D=64 -> 16/node)
    float sumsq = 0.0f;
    const int base = blockIdx.x * BLK + tid;

    if (total == 8 * STRIDE) {
        // ---- fast path: fully static, zero cross-lane ops in the loop ----
        float dots[8];
        int gs[8];
        #pragma unroll
        for (int k = 0; k < 8; k += 4) {
            f4 a[4], b[4];
            #pragma unroll
            for (int j = 0; j < 4; ++j) {
                const int i = base + (k + j) * STRIDE;
                a[j] = __builtin_nontemporal_load(x4 + i);
                b[j] = __builtin_nontemporal_load(t4 + i);
            }
            #pragma unroll
            for (int j = 0; j < 4; ++j) {
                const int n = (base + (k + j) * STRIDE) >> 4;
                gs[k + j] = is64 ? batch32[n << 1] : batch32[n];
                sumsq += sq4(a[j]) + sq4(b[j]);
                dots[k + j] = dot4(a[j], b[j]);
            }
        }
        // ---- single deferred flush ----
        #pragma unroll
        for (int k = 0; k < 8; ++k)
            red16_atomic(dots[k], gs[k], cross_lds, lane);
    } else {
        // ---- generic fallback: grid-stride with per-iter flush ----
        const int nIter = total / STRIDE;
        int idx = base;
        for (int it = 0; it < nIter; ++it, idx += STRIDE) {
            f4 a = __builtin_nontemporal_load(x4 + idx);
            f4 b = __builtin_nontemporal_load(t4 + idx);
            const int n = idx >> 4;
            const int g = is64 ? batch32[n << 1] : batch32[n];
            sumsq += sq4(a) + sq4(b);
            red16_atomic(dot4(a, b), g, cross_lds, lane);
        }
        if (idx < total) {   // ragged tail: per-thread atomic, no shuffles
            f4 a = x4[idx];
            f4 b = t4[idx];
            const int n = idx >> 4;
            const int g = is64 ? batch32[n << 1] : batch32[n];
            sumsq += sq4(a) + sq4(b);
            atomicAdd(&cross_lds[g], dot4(a, b));
        }
    }

    // Block reduction of sumsq.
    for (int m = 32; m; m >>= 1) sumsq += __shfl_xor(sumsq, m);
    if (lane == 0) redA[tid >> 6] = sumsq;
    __syncthreads();   // also orders the LDS atomics above

    if (tid < NBINS) ws[tid * GRID1 + blockIdx.x] = cross_lds[tid];
    if (tid == NBINS) {
        float s = 0.0f;
        #pragma unroll
        for (int w = 0; w < BLK / 64; ++w) s += redA[w];
        ws[NBINS * GRID1 + blockIdx.x] = s;
    }
}

// Kernel 2: 13 waves, wave w reduces column w (contiguous, coalesced), fp64.
__global__ __launch_bounds__(832) void umse_final(
    const float* __restrict__ ws, float* __restrict__ out)
{
    __shared__ double cols[13];
    const int tid = threadIdx.x;
    const int w = tid >> 6, lane = tid & 63;

    double s = 0.0;
    for (int b = lane; b < GRID1; b += 64) s += (double)ws[w * GRID1 + b];
    for (int m = 32; m; m >>= 1) s += __shfl_xor(s, m);
    if (lane == 0) cols[w] = s;
    __syncthreads();

    if (tid == 0) {
        double acc = 0.0;
        for (int g = 0; g < NBINS; ++g) acc += fabs(cols[g]);
        out[0] = (float)(cols[12] - 2.0 * acc);
    }
}

extern "C" void kernel_launch(void* const* d_in, const int* in_sizes, int n_in,
                              void* d_out, int out_size, void* d_ws, size_t ws_size,
                              hipStream_t stream)
{
    const float* x = (const float*)d_in[0];
    const float* t = (const float*)d_in[1];
    const int* batch = (const int*)d_in[2];
    const int nNodes = in_sizes[2];   // N = 262144
    float* ws = (float*)d_ws;
    float* out = (float*)d_out;

    umse_partial<<<GRID1, BLK, 0, stream>>>(
        (const f4*)x, (const f4*)t, batch, ws, nNodes);
    umse_final<<<1, 832, 0, stream>>>(ws, out);
}